// Round 7
// baseline (84.451 us; speedup 1.0000x reference)
//
#include <hip/hip_runtime.h>

// Projector: out[n][j][k] = scale * sum_t trilinear(vol, p(t)+63.5)
//   p(t) = dc + j_c[j]*u + k_c[k]*v + t_c[t]*ray,  j_c/k_c = idx-63.5
// Constants (X=Y=Z=128): n_depth=222, max_extent=96*sqrt(3), dt=2*me/221,
// scale=2*me/222.
//
// R7 == R6 with the t-window split 16 ways instead of 4 (grid x4, seg =
// blockIdx.x&3). Rationale: each wave's inner loop is a serial chain of
// dependent gathers from the 17MB table (L3-latency ~500-900cyc); occupancy
// is already maxed, so wall ~= chain length. 27 -> <=8 iters/wave cuts the
// chain 4x. Output via LDS-reduce + atomicAdd (4 partials/elem), memset node.
constexpr int ND = 222;
constexpr int Q2M = 129;                   // m in [0,129)
constexpr int Q2TOT = 129 * 129 * 128;     // xp in [0,129): 17.0 MB as uint2

__global__ __launch_bounds__(256) void pack2_kernel(
    const float* __restrict__ vol, uint2* __restrict__ Q2)
{
    const int idx = blockIdx.x * 256 + threadIdx.x;
    if (idx >= Q2TOT) return;
    const int k = idx & 127;
    const int row = idx >> 7;              // xp*129 + m
    const int xp = row / 129;
    const int m = row - xp * 129;

    float a00 = 0.0f, a01 = 0.0f, a10 = 0.0f, a11 = 0.0f;
    const int xs0 = xp - 1;                // lo x-corner
    if (xs0 >= 0) {
        const float* r = vol + xs0 * 16384 + k;
        if (m >= 1)   a00 = r[(m - 1) << 7];
        if (m <= 127) a01 = r[m << 7];
    }
    if (xp <= 127) {                       // hi x-corner
        const float* r = vol + xp * 16384 + k;
        if (m >= 1)   a10 = r[(m - 1) << 7];
        if (m <= 127) a11 = r[m << 7];
    }
    auto bf = [](float f) -> unsigned {
        unsigned u = __float_as_uint(f);
        return (u + 0x7FFF + ((u >> 16) & 1)) >> 16;
    };
    Q2[idx] = make_uint2(bf(a00) | (bf(a01) << 16), bf(a10) | (bf(a11) << 16));
}

__global__ __launch_bounds__(512) void projector_kernel(
    const float* __restrict__ vol,
    const float* __restrict__ vecs,
    const uint2* __restrict__ Q2,
    float* __restrict__ out)
{
    const int rowid = blockIdx.x >> 2;     // n*128 + j
    const int seg = blockIdx.x & 3;        // coarse t-segment 0..3
    const int n = rowid >> 7;
    const int j = rowid & 127;
    const int k = threadIdx.x & 127;
    const int th = threadIdx.x >> 7;       // sub-slice 0..3 within segment
    const int lane = threadIdx.x & 63;
    const int slice = seg * 4 + th;        // t-slice 0..15

    const float* vp = vecs + n * 12;
    const float rx = vp[0], ry = vp[1], rz = vp[2];
    const float dcx = vp[3], dcy = vp[4], dcz = vp[5];
    const float ux = vp[6], uy = vp[7], uz = vp[8];
    const float vx = vp[9], vy = vp[10], vz = vp[11];

    const float jc = (float)j - 63.5f;
    const float kc = (float)k - 63.5f;

    const float t0c = -166.2768775266122f;   // -max_extent
    const float dtc = 1.5047681223222824f;   // 2*me/221
    const float scale = 1.4979898876271372f; // 2*me/222

    __shared__ float part[4][128];

    const bool degen = (rz == 0.0f) & (uz == 0.0f) & (dcz == 0.0f) &
                       (vx == 0.0f) & (vy == 0.0f) & (vz == 1.0f);

    float acc = 0.0f;

    if (degen) {
        // Row-uniform 2D problem in x-y; z slice == k exactly (fz==0).
        const float bx = dcx + jc * ux + 63.5f;
        const float by = dcy + jc * uy + 63.5f;

        // t-window: both axes strictly inside (-0.995, 127.995) so x0,y0 in
        // [-1,127] and padded Q2 indices xp,m in [0,128] are always valid.
        float tlo = -1e30f, thi = 1e30f;
        const float bsv[2] = {bx, by};
        const float rsv[2] = {rx, ry};
        #pragma unroll
        for (int a = 0; a < 2; ++a) {
            const float b = bsv[a], r = rsv[a];
            if (fabsf(r) > 1e-8f) {
                const float inv = 1.0f / r;
                const float t1 = (-0.995f - b) * inv;
                const float t2 = (127.995f - b) * inv;
                tlo = fmaxf(tlo, fminf(t1, t2));
                thi = fminf(thi, fmaxf(t1, t2));
            } else if (b < -0.995f || b > 127.995f) {
                tlo = 1e30f; thi = -1e30f;
            }
        }
        int tb = (int)ceilf((tlo - t0c) / dtc);
        int te = (int)floorf((thi - t0c) / dtc);
        tb = max(tb, 0); te = min(te, ND - 1);

        // 16-way split of the (block-uniform) window among slices
        const int len = max(te - tb + 1, 0);
        const int q = (len + 15) >> 4;             // <= 8
        const int mtb = tb + slice * q;
        const int mte = min(mtb + q - 1, te);
        const int nact = max(mte - mtb + 1, 0);

        // ---- per-wave table: lane l -> step t = mtb + l (only l<nact used)
        {
            const float tc = fmaf(dtc, (float)(mtb + lane), t0c);
            const float ix = fmaf(tc, rx, bx);
            const float iy = fmaf(tc, ry, by);
            const float x0f = floorf(ix);
            const float y0f = floorf(iy);
            const float fx = ix - x0f;
            const float fy = iy - y0f;
            const int xp = (int)x0f + 1;           // [0,128] when used
            const int m  = (int)y0f + 1;           // [0,128] when used
            // byte offset of the (xp,m) row in Q2 (row = 128 uint2 = 1024 B)
            int t_base = (xp * Q2M + m) << 10;
            // fx in LOW half (truncated bf16), fy in HIGH half
            unsigned t_w = (__float_as_uint(fx) >> 16) |
                           (__float_as_uint(fy) & 0xFFFF0000u);
            // inner loop (wave-uniform trip count)
            const int nTab = __builtin_amdgcn_readfirstlane(nact);
            const char* q2b = (const char*)Q2 + ((unsigned)k << 3);
            for (int l = 0; l < nTab; ++l) {
                const int sb = __builtin_amdgcn_readlane(t_base, l);
                const unsigned sw =
                    (unsigned)__builtin_amdgcn_readlane((int)t_w, l);
                const float fxs = __uint_as_float(sw << 16);         // LOW  = fx
                const float fys = __uint_as_float(sw & 0xFFFF0000u); // HIGH = fy
                const uint2 qq = *(const uint2*)(q2b + sb);
                const float lo0 = __uint_as_float(qq.x << 16);
                const float hi0 = __uint_as_float(qq.x & 0xFFFF0000u);
                const float lo1 = __uint_as_float(qq.y << 16);
                const float hi1 = __uint_as_float(qq.y & 0xFFFF0000u);
                const float s0 = fmaf(fys, hi0 - lo0, lo0);  // y-lerp @ x0
                const float s1 = fmaf(fys, hi1 - lo1, lo1);  // y-lerp @ x0+1
                acc += fmaf(fxs, s1 - s0, s0);               // x-lerp
            }
        }
    } else {
        // General per-lane path (unused for this input): fp32 volume, masks.
        const float bx = dcx + jc * ux + kc * vx + 63.5f;
        const float by = dcy + jc * uy + kc * vy + 63.5f;
        const float bz = dcz + jc * uz + kc * vz + 63.5f;

        float tlo = -1e30f, thi = 1e30f;
        const float bsv[3] = {bx, by, bz};
        const float rsv[3] = {rx, ry, rz};
        #pragma unroll
        for (int a = 0; a < 3; ++a) {
            const float b = bsv[a], r = rsv[a];
            if (fabsf(r) > 1e-8f) {
                const float inv = 1.0f / r;
                const float t1 = (-1.01f - b) * inv;
                const float t2 = (128.01f - b) * inv;
                tlo = fmaxf(tlo, fminf(t1, t2));
                thi = fminf(thi, fmaxf(t1, t2));
            } else if (b < -1.01f || b > 128.01f) {
                tlo = 1e30f; thi = -1e30f;
            }
        }
        int tb = (int)ceilf((tlo - t0c) / dtc);
        int te = (int)floorf((thi - t0c) / dtc);
        const int q = 14;                      // 16*14 = 224 >= ND
        tb = max(tb, slice * q);
        te = min(te, min(slice * q + q - 1, ND - 1));

        for (int t = tb; t <= te; ++t) {
            const float tc = fmaf(dtc, (float)t, t0c);
            const float ix = fmaf(tc, rx, bx);
            const float iy = fmaf(tc, ry, by);
            const float iz = fmaf(tc, rz, bz);
            const float x0f = floorf(ix), y0f = floorf(iy), z0f = floorf(iz);
            const float fx = ix - x0f, fy = iy - y0f, fz = iz - z0f;
            const int x0 = (int)x0f, y0 = (int)y0f, z0 = (int)z0f;
            const float wx0 = ((unsigned)x0 < 128u) ? (1.0f - fx) : 0.0f;
            const float wx1 = ((unsigned)(x0 + 1) < 128u) ? fx : 0.0f;
            const float wy0 = ((unsigned)y0 < 128u) ? (1.0f - fy) : 0.0f;
            const float wy1 = ((unsigned)(y0 + 1) < 128u) ? fy : 0.0f;
            const float wz0 = ((unsigned)z0 < 128u) ? (1.0f - fz) : 0.0f;
            const float wz1 = ((unsigned)(z0 + 1) < 128u) ? fz : 0.0f;
            const int xa = min(max(x0, 0), 127) << 14;
            const int xb = min(max(x0 + 1, 0), 127) << 14;
            const int ya = min(max(y0, 0), 127) << 7;
            const int yb = min(max(y0 + 1, 0), 127) << 7;
            const int za = min(max(z0, 0), 127);
            const int zb = min(max(z0 + 1, 0), 127);
            const float w00 = wx0 * wy0, w01 = wx0 * wy1;
            const float w10 = wx1 * wy0, w11 = wx1 * wy1;
            float s0 = w00 * vol[xa + ya + za];
            s0 = fmaf(w01, vol[xa + yb + za], s0);
            s0 = fmaf(w10, vol[xb + ya + za], s0);
            s0 = fmaf(w11, vol[xb + yb + za], s0);
            float s1 = w00 * vol[xa + ya + zb];
            s1 = fmaf(w01, vol[xa + yb + zb], s1);
            s1 = fmaf(w10, vol[xb + ya + zb], s1);
            s1 = fmaf(w11, vol[xb + yb + zb], s1);
            acc = fmaf(s0, wz0, acc);
            acc = fmaf(s1, wz1, acc);
        }
    }

    // reduce the 4 sub-slices (stride-1 LDS: conflict-free), then one
    // device-scope atomic per (k, block) — 4 partials per output element.
    if (th != 0) part[th][k] = acc;
    __syncthreads();
    if (th == 0) {
        const float s = (acc + part[1][k] + part[2][k] + part[3][k]) * scale;
        atomicAdd(out + rowid * 128 + k, s);
    }
}

extern "C" void kernel_launch(void* const* d_in, const int* in_sizes, int n_in,
                              void* d_out, int out_size, void* d_ws, size_t ws_size,
                              hipStream_t stream) {
    const float* vol  = (const float*)d_in[0];   // (128,128,128) fp32
    const float* vecs = (const float*)d_in[1];   // (8,12) fp32
    float* out = (float*)d_out;                  // (8,128,128) fp32
    uint2* Q2 = (uint2*)d_ws;                    // 17 MB packed 4-corner bf16

    hipMemsetAsync(out, 0, (size_t)out_size * sizeof(float), stream);
    pack2_kernel<<<(Q2TOT + 255) / 256, 256, 0, stream>>>(vol, Q2);

    dim3 block(512);
    dim3 grid(8 * 128 * 4);                      // (n,j) rows x 4 t-segments
    projector_kernel<<<grid, block, 0, stream>>>(vol, vecs, Q2, out);
}

// Round 8
// 81.287 us; speedup vs baseline: 1.0389x; 1.0389x over previous
//
#include <hip/hip_runtime.h>

// Projector: out[n][j][k] = scale * sum_t trilinear(vol, p(t)+63.5)
//   p(t) = dc + j_c[j]*u + k_c[k]*v + t_c[t]*ray,  j_c/k_c = idx-63.5
// Constants (X=Y=Z=128): n_depth=222, max_extent=96*sqrt(3), dt=2*me/221,
// scale=2*me/222.
//
// R8 == R6 + XCD-locality swizzle. Blocks are dispatched round-robin across
// the 8 XCDs; with rowid == blockIdx, neighboring rays (which share ~75% of
// their table rows) land on DIFFERENT XCDs and same-XCD rays are 8 voxels
// apart (zero sharing) -> every XCD streams ~28MB through its 4MiB L2.
// Swizzle rowid = (blockIdx&7)*128 + blockIdx>>3: XCD c gets view n=c with
// j sweeping contiguously -> co-resident neighbor-j blocks share rows in L2.
constexpr int ND = 222;
constexpr int Q2M = 129;                   // m in [0,129)
constexpr int Q2TOT = 129 * 129 * 128;     // xp in [0,129): 17.0 MB as uint2

__global__ __launch_bounds__(256) void pack2_kernel(
    const float* __restrict__ vol, uint2* __restrict__ Q2)
{
    const int idx = blockIdx.x * 256 + threadIdx.x;
    if (idx >= Q2TOT) return;
    const int k = idx & 127;
    const int row = idx >> 7;              // xp*129 + m
    const int xp = row / 129;
    const int m = row - xp * 129;

    float a00 = 0.0f, a01 = 0.0f, a10 = 0.0f, a11 = 0.0f;
    const int xs0 = xp - 1;                // lo x-corner
    if (xs0 >= 0) {
        const float* r = vol + xs0 * 16384 + k;
        if (m >= 1)   a00 = r[(m - 1) << 7];
        if (m <= 127) a01 = r[m << 7];
    }
    if (xp <= 127) {                       // hi x-corner
        const float* r = vol + xp * 16384 + k;
        if (m >= 1)   a10 = r[(m - 1) << 7];
        if (m <= 127) a11 = r[m << 7];
    }
    auto bf = [](float f) -> unsigned {
        unsigned u = __float_as_uint(f);
        return (u + 0x7FFF + ((u >> 16) & 1)) >> 16;
    };
    Q2[idx] = make_uint2(bf(a00) | (bf(a01) << 16), bf(a10) | (bf(a11) << 16));
}

__global__ __launch_bounds__(512) void projector_kernel(
    const float* __restrict__ vol,
    const float* __restrict__ vecs,
    const uint2* __restrict__ Q2,
    float* __restrict__ out)
{
    // XCD-locality swizzle: XCD (blockIdx%8) hosts view n=blockIdx%8,
    // j = blockIdx/8 sweeps contiguously within each XCD.
    const int rowid = ((blockIdx.x & 7) << 7) | (blockIdx.x >> 3);  // n*128+j
    const int n = rowid >> 7;
    const int j = rowid & 127;
    const int k = threadIdx.x & 127;
    const int th = threadIdx.x >> 7;       // t-quarter 0..3 (2 waves each)
    const int lane = threadIdx.x & 63;

    const float* vp = vecs + n * 12;
    const float rx = vp[0], ry = vp[1], rz = vp[2];
    const float dcx = vp[3], dcy = vp[4], dcz = vp[5];
    const float ux = vp[6], uy = vp[7], uz = vp[8];
    const float vx = vp[9], vy = vp[10], vz = vp[11];

    const float jc = (float)j - 63.5f;
    const float kc = (float)k - 63.5f;

    const float t0c = -166.2768775266122f;   // -max_extent
    const float dtc = 1.5047681223222824f;   // 2*me/221
    const float scale = 1.4979898876271372f; // 2*me/222

    __shared__ float part[4][128];

    const bool degen = (rz == 0.0f) & (uz == 0.0f) & (dcz == 0.0f) &
                       (vx == 0.0f) & (vy == 0.0f) & (vz == 1.0f);

    float acc = 0.0f;

    if (degen) {
        // Row-uniform 2D problem in x-y; z slice == k exactly (fz==0).
        const float bx = dcx + jc * ux + 63.5f;
        const float by = dcy + jc * uy + 63.5f;

        // t-window: both axes strictly inside (-0.995, 127.995) so x0,y0 in
        // [-1,127] and padded Q2 indices xp,m in [0,128] are always valid.
        float tlo = -1e30f, thi = 1e30f;
        const float bsv[2] = {bx, by};
        const float rsv[2] = {rx, ry};
        #pragma unroll
        for (int a = 0; a < 2; ++a) {
            const float b = bsv[a], r = rsv[a];
            if (fabsf(r) > 1e-8f) {
                const float inv = 1.0f / r;
                const float t1 = (-0.995f - b) * inv;
                const float t2 = (127.995f - b) * inv;
                tlo = fmaxf(tlo, fminf(t1, t2));
                thi = fminf(thi, fmaxf(t1, t2));
            } else if (b < -0.995f || b > 127.995f) {
                tlo = 1e30f; thi = -1e30f;
            }
        }
        int tb = (int)ceilf((tlo - t0c) / dtc);
        int te = (int)floorf((thi - t0c) / dtc);
        tb = max(tb, 0); te = min(te, ND - 1);

        // quarter the (block-uniform) window among th
        const int len = max(te - tb + 1, 0);
        const int q = (len + 3) >> 2;              // <= 31
        const int mtb = tb + th * q;
        const int mte = min(mtb + q - 1, te);
        const int nact = max(mte - mtb + 1, 0);

        // ---- per-wave table: lane l -> step t = mtb + l (only l<nact used)
        {
            const float tc = fmaf(dtc, (float)(mtb + lane), t0c);
            const float ix = fmaf(tc, rx, bx);
            const float iy = fmaf(tc, ry, by);
            const float x0f = floorf(ix);
            const float y0f = floorf(iy);
            const float fx = ix - x0f;
            const float fy = iy - y0f;
            const int xp = (int)x0f + 1;           // [0,128] when used
            const int m  = (int)y0f + 1;           // [0,128] when used
            // byte offset of the (xp,m) row in Q2 (row = 128 uint2 = 1024 B)
            int t_base = (xp * Q2M + m) << 10;
            // fx in LOW half (truncated bf16), fy in HIGH half
            unsigned t_w = (__float_as_uint(fx) >> 16) |
                           (__float_as_uint(fy) & 0xFFFF0000u);
            // inner loop (wave-uniform trip count)
            const int nTab = __builtin_amdgcn_readfirstlane(nact);
            const char* q2b = (const char*)Q2 + ((unsigned)k << 3);
            for (int l = 0; l < nTab; ++l) {
                const int sb = __builtin_amdgcn_readlane(t_base, l);
                const unsigned sw =
                    (unsigned)__builtin_amdgcn_readlane((int)t_w, l);
                const float fxs = __uint_as_float(sw << 16);         // LOW  = fx
                const float fys = __uint_as_float(sw & 0xFFFF0000u); // HIGH = fy
                const uint2 qq = *(const uint2*)(q2b + sb);
                const float lo0 = __uint_as_float(qq.x << 16);
                const float hi0 = __uint_as_float(qq.x & 0xFFFF0000u);
                const float lo1 = __uint_as_float(qq.y << 16);
                const float hi1 = __uint_as_float(qq.y & 0xFFFF0000u);
                const float s0 = fmaf(fys, hi0 - lo0, lo0);  // y-lerp @ x0
                const float s1 = fmaf(fys, hi1 - lo1, lo1);  // y-lerp @ x0+1
                acc += fmaf(fxs, s1 - s0, s0);               // x-lerp
            }
        }
    } else {
        // General per-lane path (unused for this input): fp32 volume, masks.
        const float bx = dcx + jc * ux + kc * vx + 63.5f;
        const float by = dcy + jc * uy + kc * vy + 63.5f;
        const float bz = dcz + jc * uz + kc * vz + 63.5f;

        float tlo = -1e30f, thi = 1e30f;
        const float bsv[3] = {bx, by, bz};
        const float rsv[3] = {rx, ry, rz};
        #pragma unroll
        for (int a = 0; a < 3; ++a) {
            const float b = bsv[a], r = rsv[a];
            if (fabsf(r) > 1e-8f) {
                const float inv = 1.0f / r;
                const float t1 = (-1.01f - b) * inv;
                const float t2 = (128.01f - b) * inv;
                tlo = fmaxf(tlo, fminf(t1, t2));
                thi = fminf(thi, fmaxf(t1, t2));
            } else if (b < -1.01f || b > 128.01f) {
                tlo = 1e30f; thi = -1e30f;
            }
        }
        int tb = (int)ceilf((tlo - t0c) / dtc);
        int te = (int)floorf((thi - t0c) / dtc);
        const int q = (ND + 3) >> 2;           // 56
        tb = max(tb, th * q);
        te = min(te, min(th * q + q - 1, ND - 1));

        for (int t = tb; t <= te; ++t) {
            const float tc = fmaf(dtc, (float)t, t0c);
            const float ix = fmaf(tc, rx, bx);
            const float iy = fmaf(tc, ry, by);
            const float iz = fmaf(tc, rz, bz);
            const float x0f = floorf(ix), y0f = floorf(iy), z0f = floorf(iz);
            const float fx = ix - x0f, fy = iy - y0f, fz = iz - z0f;
            const int x0 = (int)x0f, y0 = (int)y0f, z0 = (int)z0f;
            const float wx0 = ((unsigned)x0 < 128u) ? (1.0f - fx) : 0.0f;
            const float wx1 = ((unsigned)(x0 + 1) < 128u) ? fx : 0.0f;
            const float wy0 = ((unsigned)y0 < 128u) ? (1.0f - fy) : 0.0f;
            const float wy1 = ((unsigned)(y0 + 1) < 128u) ? fy : 0.0f;
            const float wz0 = ((unsigned)z0 < 128u) ? (1.0f - fz) : 0.0f;
            const float wz1 = ((unsigned)(z0 + 1) < 128u) ? fz : 0.0f;
            const int xa = min(max(x0, 0), 127) << 14;
            const int xb = min(max(x0 + 1, 0), 127) << 14;
            const int ya = min(max(y0, 0), 127) << 7;
            const int yb = min(max(y0 + 1, 0), 127) << 7;
            const int za = min(max(z0, 0), 127);
            const int zb = min(max(z0 + 1, 0), 127);
            const float w00 = wx0 * wy0, w01 = wx0 * wy1;
            const float w10 = wx1 * wy0, w11 = wx1 * wy1;
            float s0 = w00 * vol[xa + ya + za];
            s0 = fmaf(w01, vol[xa + yb + za], s0);
            s0 = fmaf(w10, vol[xb + ya + za], s0);
            s0 = fmaf(w11, vol[xb + yb + za], s0);
            float s1 = w00 * vol[xa + ya + zb];
            s1 = fmaf(w01, vol[xa + yb + zb], s1);
            s1 = fmaf(w10, vol[xb + ya + zb], s1);
            s1 = fmaf(w11, vol[xb + yb + zb], s1);
            acc = fmaf(s0, wz0, acc);
            acc = fmaf(s1, wz1, acc);
        }
    }

    // reduce the 4 t-quarters (stride-1 LDS: conflict-free)
    if (th != 0) part[th][k] = acc;
    __syncthreads();
    if (th == 0) {
        const float s = acc + part[1][k] + part[2][k] + part[3][k];
        out[rowid * 128 + k] = s * scale;
    }
}

extern "C" void kernel_launch(void* const* d_in, const int* in_sizes, int n_in,
                              void* d_out, int out_size, void* d_ws, size_t ws_size,
                              hipStream_t stream) {
    const float* vol  = (const float*)d_in[0];   // (128,128,128) fp32
    const float* vecs = (const float*)d_in[1];   // (8,12) fp32
    float* out = (float*)d_out;                  // (8,128,128) fp32
    uint2* Q2 = (uint2*)d_ws;                    // 17 MB packed 4-corner bf16

    pack2_kernel<<<(Q2TOT + 255) / 256, 256, 0, stream>>>(vol, Q2);

    dim3 block(512);
    dim3 grid(8 * 128);                          // one block per (n,j) row
    projector_kernel<<<grid, block, 0, stream>>>(vol, vecs, Q2, out);
}